// Round 3
// baseline (934.058 us; speedup 1.0000x reference)
//
#include <hip/hip_runtime.h>

#define N_PIX 1024      // 32*32 pixels per image
#define BATCH 32
#define CCH 256         // channels == code dim
#define KCODES 4096
#define NROWS 32768     // BATCH * N_PIX

#define BROWS 32        // rows per block (4 waves x 8 rows)
#define KTILE 256       // codes per k-tile (thread t owns code k0+t for staging; lane l computes codes 4l..4l+3)
#define DCH 16          // channels per LDS chunk
#define NCHUNK ((KCODES / KTILE) * (CCH / DCH))   // 256 pipelined chunks

// ---------------- kernel 0: e_sq[k] = sum_c emb[k][c]^2 ----------------
__global__ __launch_bounds__(256) void esq_kernel(const float* __restrict__ emb,
                                                  float* __restrict__ esq) {
    const int t = threadIdx.x;
    const int w = t >> 6, l = t & 63;
    const int k = blockIdx.x * 4 + w;
    const float4 v = *(const float4*)(emb + (size_t)k * CCH + l * 4);
    float s = v.x * v.x + v.y * v.y + v.z * v.z + v.w * v.w;
#pragma unroll
    for (int off = 32; off > 0; off >>= 1) s += __shfl_down(s, off);
    if (l == 0) esq[k] = s;
}

// ---------------- kernel 1: fused distance + argmin (pipelined) ----------------
// score(n,k) = esq[k] - 2*dot(x_n, e_k)   (x_sq dropped: constant per row)
// Wave w owns rows w*8..w*8+7 (uniform -> broadcast LDS reads of xs).
// Lane l owns codes 4l..4l+3 of each 256-code tile (contiguous b128 reads).
// es[c][k] staged by thread t <-> code t: column writes es[c][t] are
// lane-consecutive dwords -> zero bank conflicts, no swizzle.
// Double-buffered es + issue-early/write-late global loads: one barrier/chunk.
__global__ __launch_bounds__(256, 2) void argmin_kernel(
    const float* __restrict__ x, const float* __restrict__ emb,
    const float* __restrict__ esq, int* __restrict__ bidx)
{
    __shared__ float xs[CCH * BROWS];        // [c][r]  32 KB, resident whole kernel
    __shared__ float es[2][DCH * KTILE];     // [c_local][k]  2 x 16 KB double buffer

    const int t = threadIdx.x;
    const int w = t >> 6;       // wave id = row group
    const int l = t & 63;       // lane   = code group
    const int n0 = blockIdx.x * BROWS;
    const int b = n0 >> 10;
    const int pixbase = n0 & (N_PIX - 1);
    const float* xb = x + (size_t)b * CCH * N_PIX + pixbase;

    // stage x tile transposed: xs[c][r] = x[b][c][pixbase+r]
    {
        const int p4 = (t & 7) * 4;
        const int crow = t >> 3;
#pragma unroll
        for (int i = 0; i < 8; ++i) {
            const int c = i * 32 + crow;
            *(float4*)(xs + c * BROWS + p4) = *(const float4*)(xb + (size_t)c * N_PIX + p4);
        }
    }

    // prologue: stage chunk 0 (k0=0, c0=0) into es[0]
    {
        const float* src = emb + (size_t)t * CCH;
        const float4 s0 = *(const float4*)(src + 0);
        const float4 s1 = *(const float4*)(src + 4);
        const float4 s2 = *(const float4*)(src + 8);
        const float4 s3 = *(const float4*)(src + 12);
        es[0][ 0 * KTILE + t] = s0.x;  es[0][ 1 * KTILE + t] = s0.y;
        es[0][ 2 * KTILE + t] = s0.z;  es[0][ 3 * KTILE + t] = s0.w;
        es[0][ 4 * KTILE + t] = s1.x;  es[0][ 5 * KTILE + t] = s1.y;
        es[0][ 6 * KTILE + t] = s1.z;  es[0][ 7 * KTILE + t] = s1.w;
        es[0][ 8 * KTILE + t] = s2.x;  es[0][ 9 * KTILE + t] = s2.y;
        es[0][10 * KTILE + t] = s2.z;  es[0][11 * KTILE + t] = s2.w;
        es[0][12 * KTILE + t] = s3.x;  es[0][13 * KTILE + t] = s3.y;
        es[0][14 * KTILE + t] = s3.z;  es[0][15 * KTILE + t] = s3.w;
    }
    __syncthreads();

    float best[8];
    int bk[8];
#pragma unroll
    for (int r = 0; r < 8; ++r) { best[r] = 3.4e38f; bk[r] = 0; }

    float acc[8][4];
#pragma unroll
    for (int r = 0; r < 8; ++r)
#pragma unroll
        for (int j = 0; j < 4; ++j) acc[r][j] = 0.f;

    for (int chunk = 0; chunk < NCHUNK; ++chunk) {
        const int buf = chunk & 1;

        // issue-early: global loads for chunk+1 (latency hides under FMAs)
        float4 s0, s1, s2, s3;
        if (chunk != NCHUNK - 1) {
            const int nk0 = ((chunk + 1) >> 4) * KTILE;
            const int nc0 = ((chunk + 1) & 15) * DCH;
            const float* src = emb + (size_t)(nk0 + t) * CCH + nc0;
            s0 = *(const float4*)(src + 0);
            s1 = *(const float4*)(src + 4);
            s2 = *(const float4*)(src + 8);
            s3 = *(const float4*)(src + 12);
        }

        // compute current chunk
        {
            const int c0 = (chunk & 15) * DCH;
            const float* ep = es[buf] + 4 * l;
            const float* xp = xs + c0 * BROWS + w * 8;
#pragma unroll
            for (int c = 0; c < DCH; ++c) {
                const float4 ev = *(const float4*)(ep + c * KTILE);
                const float4 xa = *(const float4*)(xp + c * BROWS);       // uniform -> broadcast
                const float4 xc = *(const float4*)(xp + c * BROWS + 4);   // uniform -> broadcast
                const float xr[8] = {xa.x, xa.y, xa.z, xa.w, xc.x, xc.y, xc.z, xc.w};
                const float er[4] = {ev.x, ev.y, ev.z, ev.w};
#pragma unroll
                for (int r = 0; r < 8; ++r)
#pragma unroll
                    for (int j = 0; j < 4; ++j)
                        acc[r][j] = fmaf(xr[r], er[j], acc[r][j]);
            }
        }

        // fold at end of each 256-code tile
        if ((chunk & 15) == 15) {
            const int k0 = (chunk >> 4) * KTILE;
            const float4 q = *(const float4*)(esq + k0 + 4 * l);
            const float qr[4] = {q.x, q.y, q.z, q.w};
#pragma unroll
            for (int r = 0; r < 8; ++r) {
#pragma unroll
                for (int j = 0; j < 4; ++j) {
                    const float s = fmaf(-2.f, acc[r][j], qr[j]);
                    if (s < best[r]) { best[r] = s; bk[r] = k0 + 4 * l + j; }
                    acc[r][j] = 0.f;
                }
            }
        }

        // write-late: staged regs -> other buffer (column writes, conflict-free)
        if (chunk != NCHUNK - 1) {
            float* d = es[buf ^ 1];
            d[ 0 * KTILE + t] = s0.x;  d[ 1 * KTILE + t] = s0.y;
            d[ 2 * KTILE + t] = s0.z;  d[ 3 * KTILE + t] = s0.w;
            d[ 4 * KTILE + t] = s1.x;  d[ 5 * KTILE + t] = s1.y;
            d[ 6 * KTILE + t] = s1.z;  d[ 7 * KTILE + t] = s1.w;
            d[ 8 * KTILE + t] = s2.x;  d[ 9 * KTILE + t] = s2.y;
            d[10 * KTILE + t] = s2.z;  d[11 * KTILE + t] = s2.w;
            d[12 * KTILE + t] = s3.x;  d[13 * KTILE + t] = s3.y;
            d[14 * KTILE + t] = s3.z;  d[15 * KTILE + t] = s3.w;
        }
        __syncthreads();
    }

    // cross-lane merge per row (codes are disjoint across lanes)
#pragma unroll
    for (int r = 0; r < 8; ++r) {
        float bv = best[r]; int bi = bk[r];
#pragma unroll
        for (int off = 32; off > 0; off >>= 1) {
            const float ov = __shfl_xor(bv, off, 64);
            const int   oi = __shfl_xor(bi, off, 64);
            if (ov < bv || (ov == bv && oi < bi)) { bv = ov; bi = oi; }
        }
        if (l == 0) bidx[n0 + w * 8 + r] = bi;
    }
}

// ---------------- kernel 2: gather + write oup (NCHW) + loss partials ----------------
__global__ __launch_bounds__(256) void gather_kernel(
    const float* __restrict__ x, const float* __restrict__ emb,
    const int* __restrict__ bidx, float* __restrict__ oup,
    float* __restrict__ partial)
{
    __shared__ int sidx[64];
    __shared__ float red[256];
    const int t = threadIdx.x;
    const int n0 = blockIdx.x * 64;
    const int b = n0 >> 10;
    const int pixbase = n0 & (N_PIX - 1);
    if (t < 64) sidx[t] = bidx[n0 + t];
    __syncthreads();
    const int pl = t & 63;    // pixel within tile (contiguous lanes -> coalesced x/oup)
    const int w = t >> 6;     // c quadrant
    const int k = sidx[pl];
    const float* xbp = x + (size_t)b * CCH * N_PIX + pixbase + pl;
    float* ob = oup + (size_t)b * CCH * N_PIX + pixbase + pl;
    const float* ek = emb + (size_t)k * CCH + w * 64;
    float lsum = 0.f;
#pragma unroll 4
    for (int cc = 0; cc < 16; ++cc) {
        const float4 e4 = *(const float4*)(ek + cc * 4);
        const float er[4] = {e4.x, e4.y, e4.z, e4.w};
#pragma unroll
        for (int j = 0; j < 4; ++j) {
            const size_t off = (size_t)(w * 64 + cc * 4 + j) * N_PIX;
            const float xv = xbp[off];
            ob[off] = er[j];
            const float d = xv - er[j];
            lsum = fmaf(d, d, lsum);
        }
    }
    red[t] = lsum;
    __syncthreads();
#pragma unroll
    for (int s = 128; s > 0; s >>= 1) {
        if (t < s) red[t] += red[t + s];
        __syncthreads();
    }
    if (t == 0) partial[blockIdx.x] = red[0];
}

// ---------------- kernel 3: finalize losses ----------------
__global__ __launch_bounds__(256) void finalize_kernel(const float* __restrict__ partial,
                                                       float* __restrict__ out_losses) {
    __shared__ float red[256];
    const int t = threadIdx.x;
    red[t] = partial[t] + partial[t + 256];
    __syncthreads();
    for (int s = 128; s > 0; s >>= 1) {
        if (t < s) red[t] += red[t + s];
        __syncthreads();
    }
    if (t == 0) {
        const float loss = red[0] * (1.0f / 8388608.0f);
        out_losses[0] = loss;   // dictionary_loss
        out_losses[1] = loss;   // commitment_loss (numerically identical)
    }
}

extern "C" void kernel_launch(void* const* d_in, const int* in_sizes, int n_in,
                              void* d_out, int out_size, void* d_ws, size_t ws_size,
                              hipStream_t stream) {
    const float* x = (const float*)d_in[0];
    const float* emb = (const float*)d_in[1];
    float* out = (float*)d_out;

    // workspace layout
    float* esq = (float*)d_ws;                                  // 4096 f32 (16 KB)
    int* bidx = (int*)((char*)d_ws + 16384);                    // 32768 i32 (128 KB)
    float* partial = (float*)((char*)d_ws + 16384 + 131072);    // 512 f32 (2 KB)

    esq_kernel<<<KCODES / 4, 256, 0, stream>>>(emb, esq);
    argmin_kernel<<<NROWS / BROWS, 256, 0, stream>>>(x, emb, esq, bidx);
    gather_kernel<<<NROWS / 64, 256, 0, stream>>>(x, emb, bidx, out, partial);
    finalize_kernel<<<1, 256, 0, stream>>>(partial, out + 8388608);
}